// Round 16
// baseline (403.754 us; speedup 1.0000x reference)
//
#include <hip/hip_runtime.h>

// CorrNeigh via MFMA, zero-LDS edition.
// out[b, 7*dy+j, h, w] = sum_c x[b,c,h,w] * y[b,c,h+dy-3,w+j-3]
// = S[m][n] = sum_c x[px_m,c] * y[px_n,c], diagonals scattered to out.
//
// Per block (448 thr = 7 waves): one (b, h, 64-px w0-block); wave = dy.
// Per wave: A = 4 X-tiles (16 px), B = 5 Y-tiles (16 px on the w0-4 grid),
// K = 128 channels in 4 chunks of 32 (mfma_f32_16x16x32_bf16).
// Fragments are built DIRECTLY from global loads: for k-slot j, lane l
// loads channel c_j = 4*(l>>4) + (j&3) + 16*(j>>2) (+32*kc) at pixel
// (l&15) of the tile -> 16-lane 64B coalesced segments. Any channel->slot
// bijection cancels between A and B (same sigma), so the contraction is
// correct for ANY hardware k-ordering. C/D layout (col=lane&15,
// row=4*(lane>>4)+reg) is the HW-verified mapping.
// No LDS, no barriers, no shared state: deterministic by construction.
// Edge handling: Y tiles 1..3 always in-plane; tiles 0/4 use per-lane
// clamped deltas (d0/d4) so addresses stay in-plane; invalid (lane,tile)
// fragments are zeroed via masks (pad semantics). Pad rows: gyok mask.

#define Bq 8
#define Cq 128
#define Hq 256
#define Wq 256
#define CSq (Hq * Wq)
#define NTHR 448

typedef float f32x4 __attribute__((ext_vector_type(4)));
typedef __bf16 bf16x8 __attribute__((ext_vector_type(8)));

union Frag { unsigned u[4]; bf16x8 v; };

__device__ __forceinline__ unsigned pkbf(float a, float b) {
    union { __bf16 h[2]; unsigned u; } r;
    r.h[0] = (__bf16)a; r.h[1] = (__bf16)b;
    return r.u;
}

#define MFMA_(A, B, C) __builtin_amdgcn_mfma_f32_16x16x32_bf16((A), (B), (C), 0, 0, 0)

__global__ __launch_bounds__(NTHR)
void corr7_mfma(const float* __restrict__ x, const float* __restrict__ y,
                float* __restrict__ out)
{
    const int t    = threadIdx.x;
    const int wave = t >> 6;          // dy 0..6
    const int lane = t & 63;
    const int g    = lane >> 4;       // k-group 0..3
    const int n    = lane & 15;       // free index (px within tile)

    // grid: XCD = batch (bid&7); h fastest within XCD -> y-row L2 reuse
    const int bid = (int)blockIdx.x;
    const int b   = bid & 7;
    const int id  = bid >> 3;          // 0..1023
    const int h   = id & 255;
    const int w0  = (id >> 8) << 6;    // 0,64,128,192

    const long base = (long)b * Cq * CSq;

    const int gy    = h + wave - 3;
    const bool gyok = ((unsigned)gy < (unsigned)Hq);
    const int gyc   = gyok ? gy : 0;

    // Y edge deltas: tile0 col = w0-4+n (may be <0), tile4 col = w0+60+n
    // (may be >255). Clamp ONLY those tiles' load offsets; the affected
    // lanes are exactly the masked-invalid ones, so values don't matter.
    const int d0 = (w0 == 0   && n < 4) ? (4 - n) : 0;          // >=0
    const int d4 = (w0 == 192 && n > 3) ? (3 - n) : 0;          // <=0

    const unsigned mzM = gyok ? 0xFFFFFFFFu : 0u;               // tiles 1..3
    const unsigned mz0 = (gyok && d0 == 0) ? 0xFFFFFFFFu : 0u;  // tile 0
    const unsigned mz4 = (gyok && d4 == 0) ? 0xFFFFFFFFu : 0u;  // tile 4

    // channel for k-slot j: c_j = 4g + (j&3) + 16*(j>>2)
#define CJ(J) (4 * g + ((J) & 3) + 16 * ((J) >> 2))
    const long xrow = base + (long)h * Wq + (w0 + n);
    const long yrow = base + (long)gyc * Wq + (w0 - 4 + n);
    const float* px0 = x + xrow + (long)CJ(0) * CSq;
    const float* px1 = x + xrow + (long)CJ(1) * CSq;
    const float* px2 = x + xrow + (long)CJ(2) * CSq;
    const float* px3 = x + xrow + (long)CJ(3) * CSq;
    const float* px4 = x + xrow + (long)CJ(4) * CSq;
    const float* px5 = x + xrow + (long)CJ(5) * CSq;
    const float* px6 = x + xrow + (long)CJ(6) * CSq;
    const float* px7 = x + xrow + (long)CJ(7) * CSq;
    const float* py0 = y + yrow + (long)CJ(0) * CSq;
    const float* py1 = y + yrow + (long)CJ(1) * CSq;
    const float* py2 = y + yrow + (long)CJ(2) * CSq;
    const float* py3 = y + yrow + (long)CJ(3) * CSq;
    const float* py4 = y + yrow + (long)CJ(4) * CSq;
    const float* py5 = y + yrow + (long)CJ(5) * CSq;
    const float* py6 = y + yrow + (long)CJ(6) * CSq;
    const float* py7 = y + yrow + (long)CJ(7) * CSq;
#undef CJ

    f32x4 a00 = {0.f,0.f,0.f,0.f}, a01 = a00, a10 = a00, a11 = a00;
    f32x4 a20 = a00, a21 = a00, a30 = a00, a31 = a00;

#define LOADX(F, OFF) { \
    float t0 = px0[OFF], t1 = px1[OFF], t2 = px2[OFF], t3 = px3[OFF]; \
    float t4 = px4[OFF], t5 = px5[OFF], t6 = px6[OFF], t7 = px7[OFF]; \
    F.u[0] = pkbf(t0, t1); F.u[1] = pkbf(t2, t3); \
    F.u[2] = pkbf(t4, t5); F.u[3] = pkbf(t6, t7); }

#define LOADY(F, OFF, MZ) { \
    float t0 = py0[OFF], t1 = py1[OFF], t2 = py2[OFF], t3 = py3[OFF]; \
    float t4 = py4[OFF], t5 = py5[OFF], t6 = py6[OFF], t7 = py7[OFF]; \
    F.u[0] = pkbf(t0, t1) & (MZ); F.u[1] = pkbf(t2, t3) & (MZ); \
    F.u[2] = pkbf(t4, t5) & (MZ); F.u[3] = pkbf(t6, t7) & (MZ); }

#pragma unroll 1
    for (int kc = 0; kc < 4; ++kc) {
        Frag A0, A1, A2, A3, B0, B1, B2, B3, B4;
        LOADY(B0, d0, mz0)
        LOADX(A0, 0)
        LOADY(B1, 16, mzM)
        LOADX(A1, 16)
        a00 = MFMA_(A0.v, B0.v, a00);
        a01 = MFMA_(A0.v, B1.v, a01);
        LOADY(B2, 32, mzM)
        LOADX(A2, 32)
        a10 = MFMA_(A1.v, B1.v, a10);
        a11 = MFMA_(A1.v, B2.v, a11);
        LOADY(B3, 48, mzM)
        LOADX(A3, 48)
        a20 = MFMA_(A2.v, B2.v, a20);
        a21 = MFMA_(A2.v, B3.v, a21);
        LOADY(B4, 64 + d4, mz4)
        a30 = MFMA_(A3.v, B3.v, a30);
        a31 = MFMA_(A3.v, B4.v, a31);
        // next 32 channels
        px0 += 32L * CSq; px1 += 32L * CSq; px2 += 32L * CSq; px3 += 32L * CSq;
        px4 += 32L * CSq; px5 += 32L * CSq; px6 += 32L * CSq; px7 += 32L * CSq;
        py0 += 32L * CSq; py1 += 32L * CSq; py2 += 32L * CSq; py3 += 32L * CSq;
        py4 += 32L * CSq; py5 += 32L * CSq; py6 += 32L * CSq; py7 += 32L * CSq;
    }
#undef LOADX
#undef LOADY

    // scatter diagonals: D col = n (y-px on tile nt grid), row m = 4g+r
    // (x-px = w0+16mt+m). j = ypx - xpx + 3 = 16*s + n - m - 1, keep 0..6.
    const size_t ob = ((size_t)(b * 49 + 7 * wave)) * CSq
                      + (size_t)h * Wq + w0;
#define SCAT(ACC, MT, S) { \
    _Pragma("unroll") \
    for (int r = 0; r < 4; ++r) { \
        const int dx = n + 16 * (S) - (4 * g + r) - 1; \
        if ((unsigned)dx <= 6u) \
            out[ob + (size_t)dx * CSq + 16 * (MT) + 4 * g + r] = (ACC)[r]; \
    } }
    SCAT(a00, 0, 0) SCAT(a01, 0, 1)
    SCAT(a10, 1, 0) SCAT(a11, 1, 1)
    SCAT(a20, 2, 0) SCAT(a21, 2, 1)
    SCAT(a30, 3, 0) SCAT(a31, 3, 1)
#undef SCAT
}

extern "C" void kernel_launch(void* const* d_in, const int* in_sizes, int n_in,
                              void* d_out, int out_size, void* d_ws, size_t ws_size,
                              hipStream_t stream) {
    const float* x = (const float*)d_in[0];
    const float* y = (const float*)d_in[1];
    float* out = (float*)d_out;

    dim3 grid(Bq * 256 * 4);   // 8192: 8 b x (256 h x 4 w0); XCD = b
    dim3 block(NTHR);
    hipLaunchKernelGGL(corr7_mfma, grid, block, 0, stream, x, y, out);
}